// Round 1
// baseline (479.570 us; speedup 1.0000x reference)
//
#include <hip/hip_runtime.h>

// Problem constants: B=2, T=2048, P=2048, C=1024, H=16, HD=64, S=P+T=4096
#define BB 2
#define TT 2048
#define PP 2048
#define CC 1024
#define HH 16
#define SS 4096

typedef unsigned short u16;
typedef __attribute__((ext_vector_type(8))) short s16x8;
typedef __attribute__((ext_vector_type(4))) float f32x4;
typedef __attribute__((ext_vector_type(4))) unsigned short u16x4;

// fold 1/sqrt(HD)=0.125 and log2(e) into q so softmax uses exp2 directly
#define QSCALE 0.18033688011112042f

__device__ __forceinline__ u16 f2bf(float f) {
  unsigned u = __float_as_uint(f);
  u += 0x7fff + ((u >> 16) & 1);   // RNE
  return (u16)(u >> 16);
}

// ---------------- elementwise fp32 -> bf16 (x) ----------------
__global__ __launch_bounds__(256) void cvt_f32_bf16(const float* __restrict__ src,
                                                    u16* __restrict__ dst) {
  size_t i = ((size_t)blockIdx.x * 256 + threadIdx.x) * 4;
  f32x4 v = *(const f32x4*)(src + i);
  u16x4 o = { f2bf(v[0]), f2bf(v[1]), f2bf(v[2]), f2bf(v[3]) };
  *(u16x4*)(dst + i) = o;
}

// ---------------- transpose + convert: dst[c][r] = bf16(src[r][c]) ----------------
__global__ __launch_bounds__(256) void transpose_w_bf16(const float* __restrict__ src,
                                                        u16* __restrict__ dst,
                                                        int rows, int cols) {
  __shared__ float tile[64][65];
  int r0 = blockIdx.y * 64, c0 = blockIdx.x * 64;
  int tx = threadIdx.x & 63, ty = threadIdx.x >> 6;
#pragma unroll
  for (int i = 0; i < 16; i++) {
    int r = ty + i * 4;
    tile[r][tx] = src[(size_t)(r0 + r) * cols + c0 + tx];
  }
  __syncthreads();
#pragma unroll
  for (int i = 0; i < 16; i++) {
    int cc = ty + i * 4;
    dst[(size_t)(c0 + cc) * rows + r0 + tx] = f2bf(tile[tx][cc]);
  }
}

// ---------------- cache copy: fp32 passthrough + k bf16 ----------------
__global__ __launch_bounds__(256) void cache_copy(const float* __restrict__ kc,
                                                  const float* __restrict__ vc,
                                                  float* __restrict__ kf,
                                                  float* __restrict__ vf,
                                                  u16* __restrict__ kb) {
  size_t flat = ((size_t)blockIdx.x * 256 + threadIdx.x) * 4;  // over B*P*C
  int b = (int)(flat >> 21);                   // / (P*C)
  size_t dsto = flat + (size_t)b * (TT * CC);  // insert gap of T rows per batch
  f32x4 kv = *(const f32x4*)(kc + flat);
  f32x4 vv = *(const f32x4*)(vc + flat);
  *(f32x4*)(kf + dsto) = kv;
  *(f32x4*)(vf + dsto) = vv;
  u16x4 k4 = { f2bf(kv[0]), f2bf(kv[1]), f2bf(kv[2]), f2bf(kv[3]) };
  *(u16x4*)(kb + dsto) = k4;
}

// ---------------- v_cache -> vT bf16 [B,H,HD,S] (tiled transpose) ----------------
__global__ __launch_bounds__(256) void vT_cache_kernel(const float* __restrict__ vc,
                                                       u16* __restrict__ vTb) {
  __shared__ float tile[64][65];
  int bh = blockIdx.y, b = bh >> 4, h = bh & 15;
  int p0 = blockIdx.x * 64;
  int tx = threadIdx.x & 63, ty = threadIdx.x >> 6;
#pragma unroll
  for (int i = 0; i < 16; i++) {
    int p = ty + i * 4;
    tile[p][tx] = vc[(size_t)(b * PP + p0 + p) * CC + h * 64 + tx];
  }
  __syncthreads();
#pragma unroll
  for (int i = 0; i < 16; i++) {
    int d = ty + i * 4;
    vTb[(size_t)((b * HH + h) * 64 + d) * SS + p0 + tx] = f2bf(tile[tx][d]);
  }
}

// ---------------- GEMM: C[MxN] = A[Mx1024] * BT[Nx1024]^T (bf16 MFMA) ----------------
// mode 0: plain fp32 out (ld = N). mode 1: qkv routing epilogue.
__global__ __launch_bounds__(256) void gemm_bt(const u16* __restrict__ A,
                                               const u16* __restrict__ BT,
                                               int N, int mode,
                                               float* __restrict__ out0,
                                               u16* __restrict__ qb,
                                               float* __restrict__ kf,
                                               u16* __restrict__ kb,
                                               float* __restrict__ vf,
                                               u16* __restrict__ vTb) {
  __shared__ u16 As[128 * 72];
  __shared__ u16 Bs[128 * 72];
  const int m0 = blockIdx.y * 128, n0 = blockIdx.x * 128;
  const int tid = threadIdx.x, lane = tid & 63, wave = tid >> 6;
  const int wm = wave & 1, wn = wave >> 1;
  const int c = lane & 15, quad = lane >> 4;
  const int chunk = tid & 7, rp = tid >> 3;

  f32x4 acc[4][4] = {};

  for (int k0 = 0; k0 < 1024; k0 += 64) {
#pragma unroll
    for (int it = 0; it < 4; it++) {
      int r = it * 32 + rp;
      *(s16x8*)&As[r * 72 + chunk * 8] =
          *(const s16x8*)(A + (size_t)(m0 + r) * 1024 + k0 + chunk * 8);
      *(s16x8*)&Bs[r * 72 + chunk * 8] =
          *(const s16x8*)(BT + (size_t)(n0 + r) * 1024 + k0 + chunk * 8);
    }
    __syncthreads();
#pragma unroll
    for (int kc = 0; kc < 64; kc += 32) {
      s16x8 af[4], bf[4];
#pragma unroll
      for (int i = 0; i < 4; i++) {
        af[i] = *(const s16x8*)&As[(wm * 64 + i * 16 + c) * 72 + kc + quad * 8];
        bf[i] = *(const s16x8*)&Bs[(wn * 64 + i * 16 + c) * 72 + kc + quad * 8];
      }
#pragma unroll
      for (int mi = 0; mi < 4; mi++)
#pragma unroll
        for (int ni = 0; ni < 4; ni++)
          acc[mi][ni] = __builtin_amdgcn_mfma_f32_16x16x32_bf16(af[mi], bf[ni], acc[mi][ni], 0, 0, 0);
    }
    __syncthreads();
  }

  // epilogue: C[row = m0+wm*64+mi*16+quad*4+reg][col = n0+wn*64+ni*16+c]
#pragma unroll
  for (int mi = 0; mi < 4; mi++) {
#pragma unroll
    for (int ni = 0; ni < 4; ni++) {
      f32x4 v = acc[mi][ni];
      int gmb = m0 + wm * 64 + mi * 16 + quad * 4;
      int gn = n0 + wn * 64 + ni * 16 + c;
      if (mode == 0) {
#pragma unroll
        for (int r = 0; r < 4; r++)
          out0[(size_t)(gmb + r) * N + gn] = v[r];
      } else {
        int region = n0 >> 10;  // whole block-column lies in one region
        if (region == 0) {
#pragma unroll
          for (int r = 0; r < 4; r++)
            qb[(size_t)(gmb + r) * 1024 + gn] = f2bf(v[r] * QSCALE);
        } else if (region == 1) {
          int ccol = gn - 1024;
#pragma unroll
          for (int r = 0; r < 4; r++) {
            int gm = gmb + r, b = gm >> 11, t = gm & 2047;
            size_t off = (size_t)b * (SS * CC) + (size_t)(PP + t) * CC + ccol;
            kf[off] = v[r];
            kb[off] = f2bf(v[r]);
          }
        } else {
          int ccol = gn - 2048, h = ccol >> 6, d = ccol & 63;
#pragma unroll
          for (int r = 0; r < 4; r++) {
            int gm = gmb + r, b = gm >> 11, t = gm & 2047;
            vf[(size_t)b * (SS * CC) + (size_t)(PP + t) * CC + ccol] = v[r];
            vTb[(size_t)((b * HH + h) * 64 + d) * SS + PP + t] = f2bf(v[r]);
          }
        }
      }
    }
  }
}

// ---------------- flash attention: 128 q-rows/block, 64-key tiles ----------------
__global__ __launch_bounds__(256) void attn_kernel(const u16* __restrict__ qb,
                                                   const u16* __restrict__ kb,
                                                   const u16* __restrict__ vT,
                                                   u16* __restrict__ yb) {
  __shared__ u16 Ks[64 * 72];
  __shared__ u16 Vs[64 * 72];
  __shared__ u16 Ps[4][16 * 72];
  const int bh = blockIdx.y, b = bh >> 4, h = bh & 15;
  const int qt = gridDim.x - 1 - blockIdx.x;  // heavy blocks first
  const int q0 = qt * 128;
  const int tid = threadIdx.x, lane = tid & 63, wave = tid >> 6;
  const int c = lane & 15, quad = lane >> 4;

  // Q fragments (A-layout): strips st=0,1 of 64 rows, wave owns 16 rows per strip
  s16x8 qf[2][2];
#pragma unroll
  for (int st = 0; st < 2; st++)
#pragma unroll
    for (int kc = 0; kc < 2; kc++) {
      int qr = q0 + st * 64 + wave * 16 + c;
      qf[st][kc] = *(const s16x8*)(qb + (size_t)(b * TT + qr) * 1024 + h * 64 + kc * 32 + quad * 8);
    }

  f32x4 o[2][4] = {};
  float m_r[2][4], l_r[2][4];
#pragma unroll
  for (int st = 0; st < 2; st++)
#pragma unroll
    for (int r = 0; r < 4; r++) { m_r[st][r] = -1e30f; l_r[st][r] = 0.f; }

  const int s_end = PP + q0 + 128;
  const int chunk = tid & 7, rp = tid >> 3;

  for (int s0 = 0; s0 < s_end; s0 += 64) {
#pragma unroll
    for (int it = 0; it < 2; it++) {
      int r = it * 32 + rp;
      *(s16x8*)&Ks[r * 72 + chunk * 8] =
          *(const s16x8*)(kb + (size_t)(b * SS + s0 + r) * 1024 + h * 64 + chunk * 8);
      *(s16x8*)&Vs[r * 72 + chunk * 8] =
          *(const s16x8*)(vT + (size_t)((b * HH + h) * 64 + r) * SS + s0 + chunk * 8);
    }
    __syncthreads();
    const int diag = s0 - (PP + q0);
#pragma unroll
    for (int st = 0; st < 2; st++) {
      // scores (already in exp2 domain via QSCALE)
      f32x4 sc[4];
#pragma unroll
      for (int nt = 0; nt < 4; nt++) {
        s16x8 kf0 = *(const s16x8*)&Ks[(nt * 16 + c) * 72 + quad * 8];
        s16x8 kf1 = *(const s16x8*)&Ks[(nt * 16 + c) * 72 + 32 + quad * 8];
        f32x4 z = { 0.f, 0.f, 0.f, 0.f };
        z = __builtin_amdgcn_mfma_f32_16x16x32_bf16(qf[st][0], kf0, z, 0, 0, 0);
        z = __builtin_amdgcn_mfma_f32_16x16x32_bf16(qf[st][1], kf1, z, 0, 0, 0);
        sc[nt] = z;
      }
      if (diag >= 0) {  // causal mask, only the 2 diagonal tiles
#pragma unroll
        for (int nt = 0; nt < 4; nt++) {
          int col = nt * 16 + c + diag;
#pragma unroll
          for (int r = 0; r < 4; r++) {
            int rq = st * 64 + wave * 16 + quad * 4 + r;
            if (col > rq) sc[nt][r] = -1e30f;
          }
        }
      }
      // online softmax (rows live across the 16 lanes of each quad)
      float alpha[4];
#pragma unroll
      for (int r = 0; r < 4; r++) {
        float rm = fmaxf(fmaxf(sc[0][r], sc[1][r]), fmaxf(sc[2][r], sc[3][r]));
#pragma unroll
        for (int off = 1; off < 16; off <<= 1)
          rm = fmaxf(rm, __shfl_xor(rm, off, 64));
        float mn = fmaxf(m_r[st][r], rm);
        alpha[r] = exp2f(m_r[st][r] - mn);
        m_r[st][r] = mn;
        float rs = 0.f;
#pragma unroll
        for (int nt = 0; nt < 4; nt++) {
          float p = exp2f(sc[nt][r] - mn);
          sc[nt][r] = p;
          rs += p;
        }
#pragma unroll
        for (int off = 1; off < 16; off <<= 1)
          rs += __shfl_xor(rs, off, 64);
        l_r[st][r] = l_r[st][r] * alpha[r] + rs;
      }
#pragma unroll
      for (int dt = 0; dt < 4; dt++)
#pragma unroll
        for (int r = 0; r < 4; r++) o[st][dt][r] *= alpha[r];
      // P: C/D layout -> LDS -> A layout (per-wave buffer; in-wave LDS ordering)
      u16* Pw = Ps[wave];
#pragma unroll
      for (int nt = 0; nt < 4; nt++)
#pragma unroll
        for (int r = 0; r < 4; r++)
          Pw[(quad * 4 + r) * 72 + nt * 16 + c] = f2bf(sc[nt][r]);
      s16x8 pa0 = *(const s16x8*)&Pw[c * 72 + quad * 8];
      s16x8 pa1 = *(const s16x8*)&Pw[c * 72 + 32 + quad * 8];
#pragma unroll
      for (int dt = 0; dt < 4; dt++) {
        s16x8 vb0 = *(const s16x8*)&Vs[(dt * 16 + c) * 72 + quad * 8];
        s16x8 vb1 = *(const s16x8*)&Vs[(dt * 16 + c) * 72 + 32 + quad * 8];
        o[st][dt] = __builtin_amdgcn_mfma_f32_16x16x32_bf16(pa0, vb0, o[st][dt], 0, 0, 0);
        o[st][dt] = __builtin_amdgcn_mfma_f32_16x16x32_bf16(pa1, vb1, o[st][dt], 0, 0, 0);
      }
    }
    __syncthreads();
  }
#pragma unroll
  for (int st = 0; st < 2; st++)
#pragma unroll
    for (int r = 0; r < 4; r++) {
      float inv = 1.0f / l_r[st][r];
      int qr = q0 + st * 64 + wave * 16 + quad * 4 + r;
#pragma unroll
      for (int dt = 0; dt < 4; dt++)
        yb[(size_t)(b * TT + qr) * 1024 + h * 64 + dt * 16 + c] = f2bf(o[st][dt][r] * inv);
    }
}

extern "C" void kernel_launch(void* const* d_in, const int* in_sizes, int n_in,
                              void* d_out, int out_size, void* d_ws, size_t ws_size,
                              hipStream_t stream) {
  const float* x       = (const float*)d_in[0];
  const float* k_cache = (const float*)d_in[1];
  const float* v_cache = (const float*)d_in[2];
  const float* W_attn  = (const float*)d_in[3];
  const float* W_proj  = (const float*)d_in[4];

  float* out_y = (float*)d_out;                       // [B,T,C]   4,194,304
  float* out_k = out_y + (size_t)BB * TT * CC;        // [B,S,C]   8,388,608
  float* out_v = out_k + (size_t)BB * SS * CC;        // [B,S,C]   8,388,608

  u16* xb  = (u16*)d_ws;                 // 4,194,304  x bf16
  u16* WaT = xb  + 4194304;              // 3,145,728  W_attn^T bf16 [3072,1024]
  u16* WpT = WaT + 3145728;              // 1,048,576  W_proj^T bf16 [1024,1024]
  u16* qb  = WpT + 1048576;              // 4,194,304  q bf16 (scaled) [B*T,1024]
  u16* kb  = qb  + 4194304;              // 8,388,608  k bf16 [B,S,C]
  u16* vT  = kb  + 8388608;              // 8,388,608  v^T bf16 [B,H,64,S]
  u16* yb  = vT  + 8388608;              // 4,194,304  attn out bf16 [B*T,1024]

  cvt_f32_bf16<<<dim3(4096), dim3(256), 0, stream>>>(x, xb);
  transpose_w_bf16<<<dim3(48, 16), dim3(256), 0, stream>>>(W_attn, WaT, 1024, 3072);
  transpose_w_bf16<<<dim3(16, 16), dim3(256), 0, stream>>>(W_proj, WpT, 1024, 1024);
  cache_copy<<<dim3(4096), dim3(256), 0, stream>>>(k_cache, v_cache, out_k, out_v, kb);
  vT_cache_kernel<<<dim3(32, 32), dim3(256), 0, stream>>>(v_cache, vT);
  gemm_bt<<<dim3(24, 32), dim3(256), 0, stream>>>(xb, WaT, 3072, 1, nullptr, qb, out_k, kb, out_v, vT);
  attn_kernel<<<dim3(16, 32), dim3(256), 0, stream>>>(qb, kb, vT, yb);
  gemm_bt<<<dim3(8, 32), dim3(256), 0, stream>>>(yb, WpT, 1024, 0, out_y, nullptr, nullptr, nullptr, nullptr, nullptr);
}

// Round 2
// 397.943 us; speedup vs baseline: 1.2051x; 1.2051x over previous
//
#include <hip/hip_runtime.h>

// Problem constants: B=2, T=2048, P=2048, C=1024, H=16, HD=64, S=P+T=4096
#define BB 2
#define TT 2048
#define PP 2048
#define CC 1024
#define HH 16
#define SS 4096

typedef unsigned short u16;
typedef __attribute__((ext_vector_type(8))) short s16x8;
typedef __attribute__((ext_vector_type(4))) float f32x4;
typedef __attribute__((ext_vector_type(4))) unsigned short u16x4;

// fold 1/sqrt(HD)=0.125 and log2(e) into q so softmax uses exp2 directly
#define QSCALE 0.18033688011112042f

__device__ __forceinline__ u16 f2bf(float f) {
  unsigned u = __float_as_uint(f);
  u += 0x7fff + ((u >> 16) & 1);   // RNE
  return (u16)(u >> 16);
}

// ---------------- elementwise fp32 -> bf16 (x) ----------------
__global__ __launch_bounds__(256) void cvt_f32_bf16(const float* __restrict__ src,
                                                    u16* __restrict__ dst) {
  size_t i = ((size_t)blockIdx.x * 256 + threadIdx.x) * 4;
  f32x4 v = *(const f32x4*)(src + i);
  u16x4 o = { f2bf(v[0]), f2bf(v[1]), f2bf(v[2]), f2bf(v[3]) };
  *(u16x4*)(dst + i) = o;
}

// ---------------- transpose + convert: dst[c][r] = bf16(src[r][c]) ----------------
__global__ __launch_bounds__(256) void transpose_w_bf16(const float* __restrict__ src,
                                                        u16* __restrict__ dst,
                                                        int rows, int cols) {
  __shared__ float tile[64][65];
  int r0 = blockIdx.y * 64, c0 = blockIdx.x * 64;
  int tx = threadIdx.x & 63, ty = threadIdx.x >> 6;
#pragma unroll
  for (int i = 0; i < 16; i++) {
    int r = ty + i * 4;
    tile[r][tx] = src[(size_t)(r0 + r) * cols + c0 + tx];
  }
  __syncthreads();
#pragma unroll
  for (int i = 0; i < 16; i++) {
    int cc = ty + i * 4;
    dst[(size_t)(c0 + cc) * rows + r0 + tx] = f2bf(tile[tx][cc]);
  }
}

// ---------------- cache copy: fp32 passthrough + k bf16 ----------------
__global__ __launch_bounds__(256) void cache_copy(const float* __restrict__ kc,
                                                  const float* __restrict__ vc,
                                                  float* __restrict__ kf,
                                                  float* __restrict__ vf,
                                                  u16* __restrict__ kb) {
  size_t flat = ((size_t)blockIdx.x * 256 + threadIdx.x) * 4;  // over B*P*C
  int b = (int)(flat >> 21);                   // / (P*C)
  size_t dsto = flat + (size_t)b * (TT * CC);  // insert gap of T rows per batch
  f32x4 kv = *(const f32x4*)(kc + flat);
  f32x4 vv = *(const f32x4*)(vc + flat);
  *(f32x4*)(kf + dsto) = kv;
  *(f32x4*)(vf + dsto) = vv;
  u16x4 k4 = { f2bf(kv[0]), f2bf(kv[1]), f2bf(kv[2]), f2bf(kv[3]) };
  *(u16x4*)(kb + dsto) = k4;
}

// ---------------- v_cache -> vT bf16 [B,H,HD,S] (tiled transpose) ----------------
__global__ __launch_bounds__(256) void vT_cache_kernel(const float* __restrict__ vc,
                                                       u16* __restrict__ vTb) {
  __shared__ float tile[64][65];
  int bh = blockIdx.y, b = bh >> 4, h = bh & 15;
  int p0 = blockIdx.x * 64;
  int tx = threadIdx.x & 63, ty = threadIdx.x >> 6;
#pragma unroll
  for (int i = 0; i < 16; i++) {
    int p = ty + i * 4;
    tile[p][tx] = vc[(size_t)(b * PP + p0 + p) * CC + h * 64 + tx];
  }
  __syncthreads();
#pragma unroll
  for (int i = 0; i < 16; i++) {
    int d = ty + i * 4;
    vTb[(size_t)((b * HH + h) * 64 + d) * SS + p0 + tx] = f2bf(tile[tx][d]);
  }
}

// ---------------- GEMM: C[MxN] = A[Mx1024] * BT[Nx1024]^T (bf16 MFMA) ----------------
// mode 0: plain fp32 out (ld = N). mode 1: qkv routing epilogue.
__global__ __launch_bounds__(256) void gemm_bt(const u16* __restrict__ A,
                                               const u16* __restrict__ BT,
                                               int N, int mode,
                                               float* __restrict__ out0,
                                               u16* __restrict__ qb,
                                               float* __restrict__ kf,
                                               u16* __restrict__ kb,
                                               float* __restrict__ vf,
                                               u16* __restrict__ vTb) {
  __shared__ u16 As[128 * 72];
  __shared__ u16 Bs[128 * 72];
  const int m0 = blockIdx.y * 128, n0 = blockIdx.x * 128;
  const int tid = threadIdx.x, lane = tid & 63, wave = tid >> 6;
  const int wm = wave & 1, wn = wave >> 1;
  const int c = lane & 15, quad = lane >> 4;
  const int chunk = tid & 7, rp = tid >> 3;

  f32x4 acc[4][4] = {};

  for (int k0 = 0; k0 < 1024; k0 += 64) {
#pragma unroll
    for (int it = 0; it < 4; it++) {
      int r = it * 32 + rp;
      *(s16x8*)&As[r * 72 + chunk * 8] =
          *(const s16x8*)(A + (size_t)(m0 + r) * 1024 + k0 + chunk * 8);
      *(s16x8*)&Bs[r * 72 + chunk * 8] =
          *(const s16x8*)(BT + (size_t)(n0 + r) * 1024 + k0 + chunk * 8);
    }
    __syncthreads();
#pragma unroll
    for (int kc = 0; kc < 64; kc += 32) {
      s16x8 af[4], bf[4];
#pragma unroll
      for (int i = 0; i < 4; i++) {
        af[i] = *(const s16x8*)&As[(wm * 64 + i * 16 + c) * 72 + kc + quad * 8];
        bf[i] = *(const s16x8*)&Bs[(wn * 64 + i * 16 + c) * 72 + kc + quad * 8];
      }
#pragma unroll
      for (int mi = 0; mi < 4; mi++)
#pragma unroll
        for (int ni = 0; ni < 4; ni++)
          acc[mi][ni] = __builtin_amdgcn_mfma_f32_16x16x32_bf16(af[mi], bf[ni], acc[mi][ni], 0, 0, 0);
    }
    __syncthreads();
  }

  // epilogue: C[row = m0+wm*64+mi*16+quad*4+reg][col = n0+wn*64+ni*16+c]
#pragma unroll
  for (int mi = 0; mi < 4; mi++) {
#pragma unroll
    for (int ni = 0; ni < 4; ni++) {
      f32x4 v = acc[mi][ni];
      int gmb = m0 + wm * 64 + mi * 16 + quad * 4;
      int gn = n0 + wn * 64 + ni * 16 + c;
      if (mode == 0) {
#pragma unroll
        for (int r = 0; r < 4; r++)
          out0[(size_t)(gmb + r) * N + gn] = v[r];
      } else {
        int region = n0 >> 10;  // whole block-column lies in one region
        if (region == 0) {
#pragma unroll
          for (int r = 0; r < 4; r++)
            qb[(size_t)(gmb + r) * 1024 + gn] = f2bf(v[r] * QSCALE);
        } else if (region == 1) {
          int ccol = gn - 1024;
#pragma unroll
          for (int r = 0; r < 4; r++) {
            int gm = gmb + r, b = gm >> 11, t = gm & 2047;
            size_t off = (size_t)b * (SS * CC) + (size_t)(PP + t) * CC + ccol;
            kf[off] = v[r];
            kb[off] = f2bf(v[r]);
          }
        } else {
          int ccol = gn - 2048, h = ccol >> 6, d = ccol & 63;
#pragma unroll
          for (int r = 0; r < 4; r++) {
            int gm = gmb + r, b = gm >> 11, t = gm & 2047;
            vf[(size_t)b * (SS * CC) + (size_t)(PP + t) * CC + ccol] = v[r];
            vTb[(size_t)((b * HH + h) * 64 + d) * SS + PP + t] = f2bf(v[r]);
          }
        }
      }
    }
  }
}

// ---------------- flash attention v2: 64 q-rows/block, 64-key tiles ----------------
// Wave-scalar running max (row upper bound — mathematically exact for softmax ratio),
// denominator accumulated via MFMA ones-column (Vs row 64), raw v_exp_f32.
__global__ __launch_bounds__(256) void attn_kernel(const u16* __restrict__ qb,
                                                   const u16* __restrict__ kb,
                                                   const u16* __restrict__ vT,
                                                   u16* __restrict__ yb) {
  __shared__ u16 Ks[64 * 72];
  __shared__ u16 Vs[80 * 72];      // rows 64..79: row 64 = 1.0 (ones col), 65..79 = 0
  __shared__ u16 Ps[4][16 * 72];
  const int bh = blockIdx.y, b = bh >> 4, h = bh & 15;
  const int qt = gridDim.x - 1 - blockIdx.x;  // heavy blocks first
  const int q0 = qt * 64;
  const int tid = threadIdx.x, lane = tid & 63, wave = tid >> 6;
  const int c = lane & 15, quad = lane >> 4;

  // init constant Vs rows 64..79 (row 64 = bf16(1.0), rest 0)
  for (int i = tid; i < 16 * 72; i += 256)
    Vs[64 * 72 + i] = (i < 72) ? (u16)0x3F80 : (u16)0;

  // Q fragments (A-layout): wave owns rows q0+wave*16 .. +15
  s16x8 qf[2];
#pragma unroll
  for (int kc = 0; kc < 2; kc++) {
    int qr = q0 + wave * 16 + c;
    qf[kc] = *(const s16x8*)(qb + (size_t)(b * TT + qr) * 1024 + h * 64 + kc * 32 + quad * 8);
  }

  f32x4 o[5] = {};      // o[0..3] = output d-tiles, o[4] = row-sum (ones column)
  float m = -1e30f;

  const int s_end = PP + q0 + 64;
  const int chunk = tid & 7, rp = tid >> 3;

  for (int s0 = 0; s0 < s_end; s0 += 64) {
#pragma unroll
    for (int it = 0; it < 2; it++) {
      int r = it * 32 + rp;
      *(s16x8*)&Ks[r * 72 + chunk * 8] =
          *(const s16x8*)(kb + (size_t)(b * SS + s0 + r) * 1024 + h * 64 + chunk * 8);
      *(s16x8*)&Vs[r * 72 + chunk * 8] =
          *(const s16x8*)(vT + (size_t)((b * HH + h) * 64 + r) * SS + s0 + chunk * 8);
    }
    __syncthreads();

    // scores (already in exp2 domain via QSCALE folded into q)
    f32x4 sc[4];
#pragma unroll
    for (int nt = 0; nt < 4; nt++) {
      s16x8 kf0 = *(const s16x8*)&Ks[(nt * 16 + c) * 72 + quad * 8];
      s16x8 kf1 = *(const s16x8*)&Ks[(nt * 16 + c) * 72 + 32 + quad * 8];
      f32x4 z = { 0.f, 0.f, 0.f, 0.f };
      z = __builtin_amdgcn_mfma_f32_16x16x32_bf16(qf[0], kf0, z, 0, 0, 0);
      z = __builtin_amdgcn_mfma_f32_16x16x32_bf16(qf[1], kf1, z, 0, 0, 0);
      sc[nt] = z;
    }
    const int diag = s0 - (PP + q0);
    if (diag >= 0) {  // single diagonal tile: causal mask
#pragma unroll
      for (int nt = 0; nt < 4; nt++) {
        int col = nt * 16 + c + diag;
#pragma unroll
        for (int r = 0; r < 4; r++) {
          int rq = wave * 16 + quad * 4 + r;
          if (col > rq) sc[nt][r] = -1e30f;
        }
      }
    }

    // wave-scalar max update (upper bound for all 16 rows of this wave)
    float lm = fmaxf(fmaxf(fmaxf(sc[0][0], sc[0][1]), fmaxf(sc[0][2], sc[0][3])),
                     fmaxf(fmaxf(sc[1][0], sc[1][1]), fmaxf(sc[1][2], sc[1][3])));
    lm = fmaxf(lm, fmaxf(fmaxf(fmaxf(sc[2][0], sc[2][1]), fmaxf(sc[2][2], sc[2][3])),
                         fmaxf(fmaxf(sc[3][0], sc[3][1]), fmaxf(sc[3][2], sc[3][3]))));
#pragma unroll
    for (int off = 1; off < 64; off <<= 1)
      lm = fmaxf(lm, __shfl_xor(lm, off, 64));
    if (lm > m) {                      // wave-uniform branch
      float alpha = __builtin_amdgcn_exp2f(m - lm);
      m = lm;
#pragma unroll
      for (int dt = 0; dt < 5; dt++)
#pragma unroll
        for (int r = 0; r < 4; r++) o[dt][r] *= alpha;
    }

    // p = exp2(sc - m), to bf16, C-layout -> LDS -> A-layout
    u16* Pw = Ps[wave];
#pragma unroll
    for (int nt = 0; nt < 4; nt++)
#pragma unroll
      for (int r = 0; r < 4; r++)
        Pw[(quad * 4 + r) * 72 + nt * 16 + c] = f2bf(__builtin_amdgcn_exp2f(sc[nt][r] - m));
    s16x8 pa0 = *(const s16x8*)&Pw[c * 72 + quad * 8];
    s16x8 pa1 = *(const s16x8*)&Pw[c * 72 + 32 + quad * 8];
#pragma unroll
    for (int dt = 0; dt < 5; dt++) {
      s16x8 vb0 = *(const s16x8*)&Vs[(dt * 16 + c) * 72 + quad * 8];
      s16x8 vb1 = *(const s16x8*)&Vs[(dt * 16 + c) * 72 + 32 + quad * 8];
      o[dt] = __builtin_amdgcn_mfma_f32_16x16x32_bf16(pa0, vb0, o[dt], 0, 0, 0);
      o[dt] = __builtin_amdgcn_mfma_f32_16x16x32_bf16(pa1, vb1, o[dt], 0, 0, 0);
    }
    __syncthreads();
  }

  // normalize: l for q-row (quad*4+r) lives in o[4][r] at lane c==0 of each quad
#pragma unroll
  for (int r = 0; r < 4; r++) {
    float l = __shfl(o[4][r], (lane & 48), 64);
    float inv = 1.0f / l;
    int qr = q0 + wave * 16 + quad * 4 + r;
#pragma unroll
    for (int dt = 0; dt < 4; dt++)
      yb[(size_t)(b * TT + qr) * 1024 + h * 64 + dt * 16 + c] = f2bf(o[dt][r] * inv);
  }
}

extern "C" void kernel_launch(void* const* d_in, const int* in_sizes, int n_in,
                              void* d_out, int out_size, void* d_ws, size_t ws_size,
                              hipStream_t stream) {
  const float* x       = (const float*)d_in[0];
  const float* k_cache = (const float*)d_in[1];
  const float* v_cache = (const float*)d_in[2];
  const float* W_attn  = (const float*)d_in[3];
  const float* W_proj  = (const float*)d_in[4];

  float* out_y = (float*)d_out;                       // [B,T,C]   4,194,304
  float* out_k = out_y + (size_t)BB * TT * CC;        // [B,S,C]   8,388,608
  float* out_v = out_k + (size_t)BB * SS * CC;        // [B,S,C]   8,388,608

  u16* xb  = (u16*)d_ws;                 // 4,194,304  x bf16
  u16* WaT = xb  + 4194304;              // 3,145,728  W_attn^T bf16 [3072,1024]
  u16* WpT = WaT + 3145728;              // 1,048,576  W_proj^T bf16 [1024,1024]
  u16* qb  = WpT + 1048576;              // 4,194,304  q bf16 (scaled) [B*T,1024]
  u16* kb  = qb  + 4194304;              // 8,388,608  k bf16 [B,S,C]
  u16* vT  = kb  + 8388608;              // 8,388,608  v^T bf16 [B,H,64,S]
  u16* yb  = vT  + 8388608;              // 4,194,304  attn out bf16 [B*T,1024]

  cvt_f32_bf16<<<dim3(4096), dim3(256), 0, stream>>>(x, xb);
  transpose_w_bf16<<<dim3(48, 16), dim3(256), 0, stream>>>(W_attn, WaT, 1024, 3072);
  transpose_w_bf16<<<dim3(16, 16), dim3(256), 0, stream>>>(W_proj, WpT, 1024, 1024);
  cache_copy<<<dim3(4096), dim3(256), 0, stream>>>(k_cache, v_cache, out_k, out_v, kb);
  vT_cache_kernel<<<dim3(32, 32), dim3(256), 0, stream>>>(v_cache, vT);
  gemm_bt<<<dim3(24, 32), dim3(256), 0, stream>>>(xb, WaT, 3072, 1, nullptr, qb, out_k, kb, out_v, vT);
  attn_kernel<<<dim3(32, 32), dim3(256), 0, stream>>>(qb, kb, vT, yb);
  gemm_bt<<<dim3(8, 32), dim3(256), 0, stream>>>(yb, WpT, 1024, 0, out_y, nullptr, nullptr, nullptr, nullptr, nullptr);
}

// Round 3
// 365.043 us; speedup vs baseline: 1.3137x; 1.0901x over previous
//
#include <hip/hip_runtime.h>

// Problem constants: B=2, T=2048, P=2048, C=1024, H=16, HD=64, S=P+T=4096
#define BB 2
#define TT 2048
#define PP 2048
#define CC 1024
#define HH 16
#define SS 4096

typedef unsigned short u16;
typedef __attribute__((ext_vector_type(8))) short s16x8;
typedef __attribute__((ext_vector_type(4))) float f32x4;
typedef __attribute__((ext_vector_type(4))) unsigned short u16x4;

// fold 1/sqrt(HD)=0.125 and log2(e) into q so softmax uses exp2 directly
#define QSCALE 0.18033688011112042f

__device__ __forceinline__ u16 f2bf(float f) {
  unsigned u = __float_as_uint(f);
  u += 0x7fff + ((u >> 16) & 1);   // RNE
  return (u16)(u >> 16);
}

// ---------------- elementwise fp32 -> bf16 (x) ----------------
__global__ __launch_bounds__(256) void cvt_f32_bf16(const float* __restrict__ src,
                                                    u16* __restrict__ dst) {
  size_t i = ((size_t)blockIdx.x * 256 + threadIdx.x) * 4;
  f32x4 v = *(const f32x4*)(src + i);
  u16x4 o = { f2bf(v[0]), f2bf(v[1]), f2bf(v[2]), f2bf(v[3]) };
  *(u16x4*)(dst + i) = o;
}

// ---------------- transpose + convert: dst[c][r] = bf16(src[r][c]) ----------------
__global__ __launch_bounds__(256) void transpose_w_bf16(const float* __restrict__ src,
                                                        u16* __restrict__ dst,
                                                        int rows, int cols) {
  __shared__ float tile[64][65];
  int r0 = blockIdx.y * 64, c0 = blockIdx.x * 64;
  int tx = threadIdx.x & 63, ty = threadIdx.x >> 6;
#pragma unroll
  for (int i = 0; i < 16; i++) {
    int r = ty + i * 4;
    tile[r][tx] = src[(size_t)(r0 + r) * cols + c0 + tx];
  }
  __syncthreads();
#pragma unroll
  for (int i = 0; i < 16; i++) {
    int cc = ty + i * 4;
    dst[(size_t)(c0 + cc) * rows + r0 + tx] = f2bf(tile[tx][cc]);
  }
}

// ---------------- cache copy: fp32 passthrough + k bf16 ----------------
__global__ __launch_bounds__(256) void cache_copy(const float* __restrict__ kc,
                                                  const float* __restrict__ vc,
                                                  float* __restrict__ kf,
                                                  float* __restrict__ vf,
                                                  u16* __restrict__ kb) {
  size_t flat = ((size_t)blockIdx.x * 256 + threadIdx.x) * 4;  // over B*P*C
  int b = (int)(flat >> 21);                   // / (P*C)
  size_t dsto = flat + (size_t)b * (TT * CC);  // insert gap of T rows per batch
  f32x4 kv = *(const f32x4*)(kc + flat);
  f32x4 vv = *(const f32x4*)(vc + flat);
  *(f32x4*)(kf + dsto) = kv;
  *(f32x4*)(vf + dsto) = vv;
  u16x4 k4 = { f2bf(kv[0]), f2bf(kv[1]), f2bf(kv[2]), f2bf(kv[3]) };
  *(u16x4*)(kb + dsto) = k4;
}

// ---------------- v_cache -> vT bf16 [B,H,HD,S] (tiled transpose) ----------------
__global__ __launch_bounds__(256) void vT_cache_kernel(const float* __restrict__ vc,
                                                       u16* __restrict__ vTb) {
  __shared__ float tile[64][65];
  int bh = blockIdx.y, b = bh >> 4, h = bh & 15;
  int p0 = blockIdx.x * 64;
  int tx = threadIdx.x & 63, ty = threadIdx.x >> 6;
#pragma unroll
  for (int i = 0; i < 16; i++) {
    int p = ty + i * 4;
    tile[p][tx] = vc[(size_t)(b * PP + p0 + p) * CC + h * 64 + tx];
  }
  __syncthreads();
#pragma unroll
  for (int i = 0; i < 16; i++) {
    int d = ty + i * 4;
    vTb[(size_t)((b * HH + h) * 64 + d) * SS + p0 + tx] = f2bf(tile[tx][d]);
  }
}

// ---------------- v_rem (fp32 rows PP.. of out_v) -> vT bf16 ----------------
__global__ __launch_bounds__(256) void vT_rem_kernel(const float* __restrict__ vf,
                                                     u16* __restrict__ vTb) {
  __shared__ float tile[64][65];
  int bh = blockIdx.y, b = bh >> 4, h = bh & 15;
  int p0 = blockIdx.x * 64;  // within T
  int tx = threadIdx.x & 63, ty = threadIdx.x >> 6;
#pragma unroll
  for (int i = 0; i < 16; i++) {
    int p = ty + i * 4;
    tile[p][tx] = vf[(size_t)(b * SS + PP + p0 + p) * CC + h * 64 + tx];
  }
  __syncthreads();
#pragma unroll
  for (int i = 0; i < 16; i++) {
    int d = ty + i * 4;
    vTb[(size_t)((b * HH + h) * 64 + d) * SS + PP + p0 + tx] = f2bf(tile[tx][d]);
  }
}

// ---------------- GEMM: C[MxN] = A[Mx1024] * BT[Nx1024]^T (bf16 MFMA) ----------------
// mode 0: plain fp32 out (ld = N). mode 1: qkv routing epilogue.
__global__ __launch_bounds__(256) void gemm_bt(const u16* __restrict__ A,
                                               const u16* __restrict__ BT,
                                               int N, int mode,
                                               float* __restrict__ out0,
                                               u16* __restrict__ qb,
                                               float* __restrict__ kf,
                                               u16* __restrict__ kb,
                                               float* __restrict__ vf) {
  __shared__ u16 As[128 * 72];
  __shared__ u16 Bs[128 * 72];
  const int m0 = blockIdx.y * 128, n0 = blockIdx.x * 128;
  const int tid = threadIdx.x, lane = tid & 63, wave = tid >> 6;
  const int wm = wave & 1, wn = wave >> 1;
  const int c = lane & 15, quad = lane >> 4;
  const int chunk = tid & 7, rp = tid >> 3;

  f32x4 acc[4][4] = {};

  for (int k0 = 0; k0 < 1024; k0 += 64) {
#pragma unroll
    for (int it = 0; it < 4; it++) {
      int r = it * 32 + rp;
      *(s16x8*)&As[r * 72 + chunk * 8] =
          *(const s16x8*)(A + (size_t)(m0 + r) * 1024 + k0 + chunk * 8);
      *(s16x8*)&Bs[r * 72 + chunk * 8] =
          *(const s16x8*)(BT + (size_t)(n0 + r) * 1024 + k0 + chunk * 8);
    }
    __syncthreads();
#pragma unroll
    for (int kc = 0; kc < 64; kc += 32) {
      s16x8 af[4], bf[4];
#pragma unroll
      for (int i = 0; i < 4; i++) {
        af[i] = *(const s16x8*)&As[(wm * 64 + i * 16 + c) * 72 + kc + quad * 8];
        bf[i] = *(const s16x8*)&Bs[(wn * 64 + i * 16 + c) * 72 + kc + quad * 8];
      }
#pragma unroll
      for (int mi = 0; mi < 4; mi++)
#pragma unroll
        for (int ni = 0; ni < 4; ni++)
          acc[mi][ni] = __builtin_amdgcn_mfma_f32_16x16x32_bf16(af[mi], bf[ni], acc[mi][ni], 0, 0, 0);
    }
    __syncthreads();
  }

  // epilogue: C[row = m0+wm*64+mi*16+quad*4+reg][col = n0+wn*64+ni*16+c]
#pragma unroll
  for (int mi = 0; mi < 4; mi++) {
#pragma unroll
    for (int ni = 0; ni < 4; ni++) {
      f32x4 v = acc[mi][ni];
      int gmb = m0 + wm * 64 + mi * 16 + quad * 4;
      int gn = n0 + wn * 64 + ni * 16 + c;
      if (mode == 0) {
#pragma unroll
        for (int r = 0; r < 4; r++)
          out0[(size_t)(gmb + r) * N + gn] = v[r];
      } else {
        int region = n0 >> 10;  // whole block-column lies in one region
        if (region == 0) {
#pragma unroll
          for (int r = 0; r < 4; r++)
            qb[(size_t)(gmb + r) * 1024 + gn] = f2bf(v[r] * QSCALE);
        } else if (region == 1) {
          int ccol = gn - 1024;
#pragma unroll
          for (int r = 0; r < 4; r++) {
            int gm = gmb + r, b = gm >> 11, t = gm & 2047;
            size_t off = (size_t)b * (SS * CC) + (size_t)(PP + t) * CC + ccol;
            kf[off] = v[r];
            kb[off] = f2bf(v[r]);
          }
        } else {
          int ccol = gn - 2048;
#pragma unroll
          for (int r = 0; r < 4; r++) {
            int gm = gmb + r, b = gm >> 11, t = gm & 2047;
            vf[(size_t)b * (SS * CC) + (size_t)(PP + t) * CC + ccol] = v[r];
          }
        }
      }
    }
  }
}

// ---------------- flash attention v3: 128 q-rows/block, wave = 2x16-row strips ----------------
// K/V fragment reads shared across both strips; wave-scalar running max; denominator
// via hoisted MFMA ones-column; raw v_exp_f32.
__global__ __launch_bounds__(256) void attn_kernel(const u16* __restrict__ qb,
                                                   const u16* __restrict__ kb,
                                                   const u16* __restrict__ vT,
                                                   u16* __restrict__ yb) {
  __shared__ u16 Ks[64 * 72];
  __shared__ u16 Vs[80 * 72];      // rows 64..79: row 64 = 1.0 (ones col), 65..79 = 0
  __shared__ u16 Ps[4][32 * 72];
  const int bh = blockIdx.y, b = bh >> 4, h = bh & 15;
  const int qt = gridDim.x - 1 - blockIdx.x;  // heavy blocks first
  const int q0 = qt * 128;
  const int tid = threadIdx.x, lane = tid & 63, wave = tid >> 6;
  const int c = lane & 15, quad = lane >> 4;

  // init constant Vs rows 64..79 (row 64 = bf16(1.0), rest 0)
  for (int i = tid; i < 16 * 72; i += 256)
    Vs[64 * 72 + i] = (i < 72) ? (u16)0x3F80 : (u16)0;
  __syncthreads();
  const s16x8 ones0 = *(const s16x8*)&Vs[(64 + c) * 72 + quad * 8];
  const s16x8 ones1 = *(const s16x8*)&Vs[(64 + c) * 72 + 32 + quad * 8];

  // Q fragments (A-layout): wave owns rows q0 + wave*32 + st*16 + (0..15)
  s16x8 qf[2][2];
#pragma unroll
  for (int st = 0; st < 2; st++)
#pragma unroll
    for (int kc = 0; kc < 2; kc++) {
      int qr = q0 + wave * 32 + st * 16 + c;
      qf[st][kc] = *(const s16x8*)(qb + (size_t)(b * TT + qr) * 1024 + h * 64 + kc * 32 + quad * 8);
    }

  f32x4 o[2][5] = {};   // per strip: [0..3] output d-tiles, [4] row-sum
  float m = -1e30f;

  const int s_end = PP + q0 + 128;
  const int chunk = tid & 7, rp = tid >> 3;

  for (int s0 = 0; s0 < s_end; s0 += 64) {
#pragma unroll
    for (int it = 0; it < 2; it++) {
      int r = it * 32 + rp;
      *(s16x8*)&Ks[r * 72 + chunk * 8] =
          *(const s16x8*)(kb + (size_t)(b * SS + s0 + r) * 1024 + h * 64 + chunk * 8);
      *(s16x8*)&Vs[r * 72 + chunk * 8] =
          *(const s16x8*)(vT + (size_t)((b * HH + h) * 64 + r) * SS + s0 + chunk * 8);
    }
    __syncthreads();

    // scores for both strips, K-frags read once
    f32x4 sc[2][4];
#pragma unroll
    for (int nt = 0; nt < 4; nt++) {
      s16x8 kf0 = *(const s16x8*)&Ks[(nt * 16 + c) * 72 + quad * 8];
      s16x8 kf1 = *(const s16x8*)&Ks[(nt * 16 + c) * 72 + 32 + quad * 8];
#pragma unroll
      for (int st = 0; st < 2; st++) {
        f32x4 z = { 0.f, 0.f, 0.f, 0.f };
        z = __builtin_amdgcn_mfma_f32_16x16x32_bf16(qf[st][0], kf0, z, 0, 0, 0);
        z = __builtin_amdgcn_mfma_f32_16x16x32_bf16(qf[st][1], kf1, z, 0, 0, 0);
        sc[st][nt] = z;
      }
    }
    const int diag = s0 - (PP + q0);
    if (diag >= 0) {  // causal mask (block diagonal region spans 2 tiles)
#pragma unroll
      for (int st = 0; st < 2; st++)
#pragma unroll
        for (int nt = 0; nt < 4; nt++) {
          int col = nt * 16 + c + diag;
#pragma unroll
          for (int r = 0; r < 4; r++) {
            int rq = wave * 32 + st * 16 + quad * 4 + r;
            if (col > rq) sc[st][nt][r] = -1e30f;
          }
        }
    }

    // wave-scalar max update (upper bound for all 32 rows of this wave)
    float lm = -1e30f;
#pragma unroll
    for (int st = 0; st < 2; st++)
#pragma unroll
      for (int nt = 0; nt < 4; nt++)
        lm = fmaxf(lm, fmaxf(fmaxf(sc[st][nt][0], sc[st][nt][1]),
                             fmaxf(sc[st][nt][2], sc[st][nt][3])));
#pragma unroll
    for (int off = 1; off < 64; off <<= 1)
      lm = fmaxf(lm, __shfl_xor(lm, off, 64));
    if (lm > m) {                      // wave-uniform branch
      float alpha = __builtin_amdgcn_exp2f(m - lm);
      m = lm;
#pragma unroll
      for (int st = 0; st < 2; st++)
#pragma unroll
        for (int dt = 0; dt < 5; dt++)
#pragma unroll
          for (int r = 0; r < 4; r++) o[st][dt][r] *= alpha;
    }

    // p = exp2(sc - m), to bf16, C-layout -> LDS -> A-layout (both strips)
    u16* Pw = Ps[wave];
#pragma unroll
    for (int st = 0; st < 2; st++)
#pragma unroll
      for (int nt = 0; nt < 4; nt++)
#pragma unroll
        for (int r = 0; r < 4; r++)
          Pw[(st * 16 + quad * 4 + r) * 72 + nt * 16 + c] =
              f2bf(__builtin_amdgcn_exp2f(sc[st][nt][r] - m));
    s16x8 pa[2][2];
#pragma unroll
    for (int st = 0; st < 2; st++) {
      pa[st][0] = *(const s16x8*)&Pw[(st * 16 + c) * 72 + quad * 8];
      pa[st][1] = *(const s16x8*)&Pw[(st * 16 + c) * 72 + 32 + quad * 8];
    }
#pragma unroll
    for (int dt = 0; dt < 4; dt++) {
      s16x8 vb0 = *(const s16x8*)&Vs[(dt * 16 + c) * 72 + quad * 8];
      s16x8 vb1 = *(const s16x8*)&Vs[(dt * 16 + c) * 72 + 32 + quad * 8];
#pragma unroll
      for (int st = 0; st < 2; st++) {
        o[st][dt] = __builtin_amdgcn_mfma_f32_16x16x32_bf16(pa[st][0], vb0, o[st][dt], 0, 0, 0);
        o[st][dt] = __builtin_amdgcn_mfma_f32_16x16x32_bf16(pa[st][1], vb1, o[st][dt], 0, 0, 0);
      }
    }
#pragma unroll
    for (int st = 0; st < 2; st++) {
      o[st][4] = __builtin_amdgcn_mfma_f32_16x16x32_bf16(pa[st][0], ones0, o[st][4], 0, 0, 0);
      o[st][4] = __builtin_amdgcn_mfma_f32_16x16x32_bf16(pa[st][1], ones1, o[st][4], 0, 0, 0);
    }
    __syncthreads();
  }

  // normalize: l for q-row (quad*4+r) lives in o[st][4][r] at lane c==0 of each quad
#pragma unroll
  for (int st = 0; st < 2; st++)
#pragma unroll
    for (int r = 0; r < 4; r++) {
      float l = __shfl(o[st][4][r], (lane & 48), 64);
      float inv = 1.0f / l;
      int qr = q0 + wave * 32 + st * 16 + quad * 4 + r;
#pragma unroll
      for (int dt = 0; dt < 4; dt++)
        yb[(size_t)(b * TT + qr) * 1024 + h * 64 + dt * 16 + c] = f2bf(o[st][dt][r] * inv);
    }
}

extern "C" void kernel_launch(void* const* d_in, const int* in_sizes, int n_in,
                              void* d_out, int out_size, void* d_ws, size_t ws_size,
                              hipStream_t stream) {
  const float* x       = (const float*)d_in[0];
  const float* k_cache = (const float*)d_in[1];
  const float* v_cache = (const float*)d_in[2];
  const float* W_attn  = (const float*)d_in[3];
  const float* W_proj  = (const float*)d_in[4];

  float* out_y = (float*)d_out;                       // [B,T,C]   4,194,304
  float* out_k = out_y + (size_t)BB * TT * CC;        // [B,S,C]   8,388,608
  float* out_v = out_k + (size_t)BB * SS * CC;        // [B,S,C]   8,388,608

  u16* xb  = (u16*)d_ws;                 // 4,194,304  x bf16
  u16* WaT = xb  + 4194304;              // 3,145,728  W_attn^T bf16 [3072,1024]
  u16* WpT = WaT + 3145728;              // 1,048,576  W_proj^T bf16 [1024,1024]
  u16* qb  = WpT + 1048576;              // 4,194,304  q bf16 (scaled) [B*T,1024]
  u16* kb  = qb  + 4194304;              // 8,388,608  k bf16 [B,S,C]
  u16* vT  = kb  + 8388608;              // 8,388,608  v^T bf16 [B,H,64,S]
  u16* yb  = vT  + 8388608;              // 4,194,304  attn out bf16 [B*T,1024]

  cvt_f32_bf16<<<dim3(4096), dim3(256), 0, stream>>>(x, xb);
  transpose_w_bf16<<<dim3(48, 16), dim3(256), 0, stream>>>(W_attn, WaT, 1024, 3072);
  transpose_w_bf16<<<dim3(16, 16), dim3(256), 0, stream>>>(W_proj, WpT, 1024, 1024);
  cache_copy<<<dim3(4096), dim3(256), 0, stream>>>(k_cache, v_cache, out_k, out_v, kb);
  vT_cache_kernel<<<dim3(32, 32), dim3(256), 0, stream>>>(v_cache, vT);
  gemm_bt<<<dim3(24, 32), dim3(256), 0, stream>>>(xb, WaT, 3072, 1, nullptr, qb, out_k, kb, out_v);
  vT_rem_kernel<<<dim3(32, 32), dim3(256), 0, stream>>>(out_v, vT);
  attn_kernel<<<dim3(16, 32), dim3(256), 0, stream>>>(qb, kb, vT, yb);
  gemm_bt<<<dim3(8, 32), dim3(256), 0, stream>>>(yb, WpT, 1024, 0, out_y, nullptr, nullptr, nullptr, nullptr);
}